// Round 1
// baseline (347.594 us; speedup 1.0000x reference)
//
#include <hip/hip_runtime.h>
#include <math.h>

#define Bb 16
#define Nn 1024
#define Dd 16
#define NL 15

// ---------------------------------------------------------------------------
// Layer 0: Z[:,:,0] = (X[:,:,0]-mu0)*exp(-a0); logdet base = -a0
// ---------------------------------------------------------------------------
__global__ void gf_init(const float* __restrict__ X, const float* __restrict__ ip,
                        float* __restrict__ out) {
    int idx = blockIdx.x * blockDim.x + threadIdx.x;   // over B*N
    if (idx >= Bb * Nn) return;
    float mu = ip[0], alpha = ip[1];
    float x0 = X[(size_t)idx * Dd];
    out[(size_t)idx * Dd] = (x0 - mu) * __expf(-alpha);     // Z[b,n,0]
    out[(size_t)Bb * Nn * Dd + idx] = -alpha;               // logdet[b,n]
}

// project one 16-float x-row through W[:i,:i]^T + bias, zero-padded to 16
__device__ __forceinline__ void project(const float* __restrict__ xrow,
                                        const float* __restrict__ W,
                                        const float* __restrict__ bias,
                                        int i, float* __restrict__ q) {
#pragma unroll
    for (int r = 0; r < 16; r++) q[r] = 0.f;
    for (int c = 0; c < i; c++) {
        float xc = xrow[c];
#pragma unroll
        for (int r = 0; r < 16; r++) q[r] = fmaf(xc, W[r * 16 + c], q[r]);
    }
#pragma unroll
    for (int r = 0; r < 16; r++) q[r] = (r < i) ? (q[r] + bias[r]) : 0.f;
}

__device__ __forceinline__ void load_row16(const float* __restrict__ p, float* __restrict__ x) {
    const float4* xp = (const float4*)p;
    float4 a = xp[0], b = xp[1], c = xp[2], d = xp[3];
    x[0]=a.x; x[1]=a.y; x[2]=a.z; x[3]=a.w;
    x[4]=b.x; x[5]=b.y; x[6]=b.z; x[7]=b.w;
    x[8]=c.x; x[9]=c.y; x[10]=c.z; x[11]=c.w;
    x[12]=d.x; x[13]=d.y; x[14]=d.z; x[15]=d.w;
}

// ---------------------------------------------------------------------------
// One block per (layer l = blockIdx.x, batch b = blockIdx.y).
// 512 threads, 2 query rows each. K/V tiles of 512 keys in LDS (64 KB).
// Online softmax with fixed max=0 (scores are tiny: W-scale 0.05).
// ---------------------------------------------------------------------------
__launch_bounds__(512, 2)
__global__ void gf_layer(const float* __restrict__ X,
                         const float* __restrict__ Wq, const float* __restrict__ bq,
                         const float* __restrict__ Wk, const float* __restrict__ bk,
                         const float* __restrict__ Wv, const float* __restrict__ bv,
                         const float* __restrict__ Wo, const float* __restrict__ bo,
                         const float* __restrict__ Wf, const float* __restrict__ bf,
                         float* __restrict__ out) {
    const int l = blockIdx.x;          // 0..14
    const int b = blockIdx.y;          // 0..15
    const int i = l + 1;               // active feature count
    const int t = threadIdx.x;         // 0..511
    const float rscale = rsqrtf((float)i);

    __shared__ float Ksh[512 * 16];
    __shared__ float Vsh[512 * 16];

    const float* Xb  = X  + (size_t)b * Nn * Dd;
    const float* wq  = Wq + l * 256;
    const float* wk  = Wk + l * 256;
    const float* wv  = Wv + l * 256;
    const float* wo  = Wo + l * 256;
    const float* wf  = Wf + l * 32;
    const float* bql = bq + l * 16;
    const float* bkl = bk + l * 16;
    const float* bvl = bv + l * 16;
    const float* bol = bo + l * 16;
    const float* bfl = bf + l * 2;

    const int n0 = t, n1 = t + 512;

    // ---- Q projections for this thread's two query rows ----
    float q0[16], q1[16];
    float xi0, xi1;
    {
        float xr[16];
        load_row16(Xb + (size_t)n0 * Dd, xr);
        xi0 = xr[i];
        project(xr, wq, bql, i, q0);
        load_row16(Xb + (size_t)n1 * Dd, xr);
        xi1 = xr[i];
        project(xr, wq, bql, i, q1);
    }

    float o0[16], o1[16];
#pragma unroll
    for (int c = 0; c < 16; c++) { o0[c] = 0.f; o1[c] = 0.f; }
    float ls0 = 0.f, ls1 = 0.f;

    // ---- attention over 2 key chunks of 512 ----
    for (int ch = 0; ch < 2; ch++) {
        // stage K,V for key row (ch*512 + t)
        float kr[16], vr[16];
        {
            float kx[16];
            load_row16(Xb + (size_t)(ch * 512 + t) * Dd, kx);
            project(kx, wk, bkl, i, kr);
            project(kx, wv, bvl, i, vr);
        }
        __syncthreads();   // previous chunk fully consumed
#pragma unroll
        for (int j = 0; j < 4; j++) {
            ((float4*)&Ksh[t * 16])[j] = ((float4*)kr)[j];
            ((float4*)&Vsh[t * 16])[j] = ((float4*)vr)[j];
        }
        __syncthreads();   // staging visible

        for (int k = 0; k < 512; k++) {
            float kk[16], vv[16];
#pragma unroll
            for (int j = 0; j < 4; j++)
                ((float4*)kk)[j] = ((const float4*)&Ksh[k * 16])[j];
            float s0 = 0.f, s1 = 0.f;
#pragma unroll
            for (int c = 0; c < 16; c++) {
                s0 = fmaf(q0[c], kk[c], s0);
                s1 = fmaf(q1[c], kk[c], s1);
            }
            float p0 = __expf(s0 * rscale);
            float p1 = __expf(s1 * rscale);
            ls0 += p0; ls1 += p1;
#pragma unroll
            for (int j = 0; j < 4; j++)
                ((float4*)vv)[j] = ((const float4*)&Vsh[k * 16])[j];
#pragma unroll
            for (int c = 0; c < 16; c++) {
                o0[c] = fmaf(p0, vv[c], o0[c]);
                o1[c] = fmaf(p1, vv[c], o1[c]);
            }
        }
        __syncthreads();   // done reading before next stage overwrites
    }

    // ---- epilogue for both rows: O=Q+A@V; O+=relu(O@Wo^T+bo); head; Z ----
    float* logdet = out + (size_t)Bb * Nn * Dd;
#pragma unroll
    for (int rowsel = 0; rowsel < 2; rowsel++) {
        const float* qr = rowsel ? q1 : q0;
        const float* orr = rowsel ? o1 : o0;
        float lsum = rowsel ? ls1 : ls0;
        float xin  = rowsel ? xi1 : xi0;
        int n      = rowsel ? n1 : n0;

        float a[16];
        float inv = 1.f / lsum;
#pragma unroll
        for (int c = 0; c < 16; c++) a[c] = qr[c] + orr[c] * inv;  // c>=i stays 0

        float tt[16];
#pragma unroll
        for (int r = 0; r < 16; r++) {
            float acc = bol[r];
#pragma unroll
            for (int c = 0; c < 16; c++) acc = fmaf(a[c], wo[r * 16 + c], acc);
            tt[r] = fmaxf(acc, 0.f);
        }
#pragma unroll
        for (int r = 0; r < 16; r++) a[r] += (r < i) ? tt[r] : 0.f;

        float mu = bfl[0], al = bfl[1];
#pragma unroll
        for (int c = 0; c < 16; c++) {
            mu = fmaf(a[c], wf[c], mu);
            al = fmaf(a[c], wf[16 + c], al);
        }
        out[((size_t)(b * Nn + n)) * Dd + i] = (xin - mu) * __expf(-al);
        atomicAdd(logdet + b * Nn + n, -al);
    }
}

extern "C" void kernel_launch(void* const* d_in, const int* in_sizes, int n_in,
                              void* d_out, int out_size, void* d_ws, size_t ws_size,
                              hipStream_t stream) {
    const float* X  = (const float*)d_in[0];
    const float* ip = (const float*)d_in[1];
    const float* Wq = (const float*)d_in[2];
    const float* bq = (const float*)d_in[3];
    const float* Wk = (const float*)d_in[4];
    const float* bk = (const float*)d_in[5];
    const float* Wv = (const float*)d_in[6];
    const float* bv = (const float*)d_in[7];
    const float* Wo = (const float*)d_in[8];
    const float* bo = (const float*)d_in[9];
    const float* Wf = (const float*)d_in[10];
    const float* bf = (const float*)d_in[11];
    float* out = (float*)d_out;

    gf_init<<<(Bb * Nn + 255) / 256, 256, 0, stream>>>(X, ip, out);
    gf_layer<<<dim3(NL, Bb), 512, 0, stream>>>(X, Wq, bq, Wk, bk, Wv, bv,
                                               Wo, bo, Wf, bf, out);
}

// Round 2
// 250.604 us; speedup vs baseline: 1.3870x; 1.3870x over previous
//
#include <hip/hip_runtime.h>
#include <math.h>

#define Bb 16
#define Nn 1024
#define Dd 16
#define NL 15

typedef __attribute__((ext_vector_type(8))) short short8;
typedef __attribute__((ext_vector_type(4))) float f32x4;

#if __has_builtin(__builtin_amdgcn_exp2f)
#define EXP2(x) __builtin_amdgcn_exp2f(x)
#else
#define EXP2(x) exp2f(x)
#endif

// round-to-nearest-even fp32 -> bf16 (packed pair into one uint)
__device__ __forceinline__ unsigned pack2bf(float a, float b) {
    unsigned ua = __float_as_uint(a); ua += 0x7fffu + ((ua >> 16) & 1u);
    unsigned ub = __float_as_uint(b); ub += 0x7fffu + ((ub >> 16) & 1u);
    return (ua >> 16) | (ub & 0xffff0000u);
}
__device__ __forceinline__ unsigned short bf1(float a) {
    unsigned ua = __float_as_uint(a); ua += 0x7fffu + ((ua >> 16) & 1u);
    return (unsigned short)(ua >> 16);
}

// project one 16-float x-row through W[:i,:i]^T + bias, zero-padded to 16
__device__ __forceinline__ void project(const float* __restrict__ xrow,
                                        const float* __restrict__ W,
                                        const float* __restrict__ bias,
                                        int i, float* __restrict__ q) {
#pragma unroll
    for (int r = 0; r < 16; r++) q[r] = 0.f;
    for (int c = 0; c < i; c++) {
        float xc = xrow[c];
#pragma unroll
        for (int r = 0; r < 16; r++) q[r] = fmaf(xc, W[r * 16 + c], q[r]);
    }
#pragma unroll
    for (int r = 0; r < 16; r++) q[r] = (r < i) ? (q[r] + bias[r]) : 0.f;
}

__device__ __forceinline__ void load_row16(const float* __restrict__ p, float* __restrict__ x) {
    const float4* xp = (const float4*)p;
    float4 a = xp[0], b = xp[1], c = xp[2], d = xp[3];
    x[0]=a.x; x[1]=a.y; x[2]=a.z; x[3]=a.w;
    x[4]=b.x; x[5]=b.y; x[6]=b.z; x[7]=b.w;
    x[8]=c.x; x[9]=c.y; x[10]=c.z; x[11]=c.w;
    x[12]=d.x; x[13]=d.y; x[14]=d.z; x[15]=d.w;
}

// ---------------------------------------------------------------------------
// Layer 0
// ---------------------------------------------------------------------------
__global__ void gf_init(const float* __restrict__ X, const float* __restrict__ ip,
                        float* __restrict__ out) {
    int idx = blockIdx.x * blockDim.x + threadIdx.x;
    if (idx >= Bb * Nn) return;
    float mu = ip[0], alpha = ip[1];
    float x0 = X[(size_t)idx * Dd];
    out[(size_t)idx * Dd] = (x0 - mu) * __expf(-alpha);
    out[(size_t)Bb * Nn * Dd + idx] = -alpha;
}

// ---------------------------------------------------------------------------
// Projection: Qb (bf16, scaled by log2e/sqrt(i)), Kb (bf16), Vt (bf16, [d][n])
// grid (NL, Bb), 256 threads, 4 rows/thread
// ---------------------------------------------------------------------------
__launch_bounds__(256)
__global__ void gf_proj(const float* __restrict__ X,
                        const float* __restrict__ Wq, const float* __restrict__ bq,
                        const float* __restrict__ Wk, const float* __restrict__ bk,
                        const float* __restrict__ Wv, const float* __restrict__ bv,
                        unsigned short* __restrict__ Qb,
                        unsigned short* __restrict__ Kb,
                        unsigned short* __restrict__ Vt) {
    const int l = blockIdx.x, b = blockIdx.y, i = l + 1, t = threadIdx.x;
    const int lb = l * Bb + b;
    const float qscale = 1.4426950408889634f * rsqrtf((float)i);   // log2(e)/sqrt(i)
    const float* Xb = X + (size_t)b * Nn * Dd;
    const float* wq = Wq + l * 256;  const float* bql = bq + l * 16;
    const float* wk = Wk + l * 256;  const float* bkl = bk + l * 16;
    const float* wv = Wv + l * 256;  const float* bvl = bv + l * 16;

#pragma unroll
    for (int j = 0; j < 4; j++) {
        const int n = t + j * 256;
        float xr[16]; load_row16(Xb + (size_t)n * Dd, xr);
        float q[16], k[16], v[16];
        project(xr, wq, bql, i, q);
        project(xr, wk, bkl, i, k);
        project(xr, wv, bvl, i, v);
        const size_t row = (size_t)lb * Nn + n;
        unsigned uq[8], uk[8];
#pragma unroll
        for (int r = 0; r < 8; r++) {
            uq[r] = pack2bf(q[2*r] * qscale, q[2*r+1] * qscale);
            uk[r] = pack2bf(k[2*r], k[2*r+1]);
        }
        uint4* qdst = (uint4*)(Qb + row * 16);
        qdst[0] = make_uint4(uq[0], uq[1], uq[2], uq[3]);
        qdst[1] = make_uint4(uq[4], uq[5], uq[6], uq[7]);
        uint4* kdst = (uint4*)(Kb + row * 16);
        kdst[0] = make_uint4(uk[0], uk[1], uk[2], uk[3]);
        kdst[1] = make_uint4(uk[4], uk[5], uk[6], uk[7]);
        unsigned short* vt = Vt + (size_t)lb * (Dd * Nn) + n;
#pragma unroll
        for (int d = 0; d < 16; d++) vt[d * Nn] = bf1(v[d]);
    }
}

// ---------------------------------------------------------------------------
// MFMA attention: Oa = softmax(Q K^T / sqrt(i)) @ V   (per (l,b), padded d=16)
// grid (16 qblocks, NL, Bb), 256 threads = 4 waves, wave = 16 queries.
// S^T = mfma(A=K, B=Q); P via exp2; P -> LDS (b64) -> b128 A...B-frag;
// O^T = mfma(A=V^T, B=P^T).   Verified 16x16x32 layouts only.
// ---------------------------------------------------------------------------
#define PSTR 136   // LDS row stride in bf16 elems (16B-aligned rows, depads banks)
__launch_bounds__(256, 4)
__global__ void gf_attn(const unsigned short* __restrict__ Qb,
                        const unsigned short* __restrict__ Kb,
                        const unsigned short* __restrict__ Vt,
                        float* __restrict__ Oa) {
    const int qblk = blockIdx.x, l = blockIdx.y, b = blockIdx.z;
    const int lb = l * Bb + b;
    const int t = threadIdx.x, wid = t >> 6, lane = t & 63;
    const int c15 = lane & 15, quad = lane >> 4;
    const int qbase = qblk * 64 + wid * 16;

    __shared__ unsigned short Pl[4 * 16 * PSTR];
    unsigned short* prow = Pl + wid * 16 * PSTR + c15 * PSTR;

    short8 zero8 = {0,0,0,0,0,0,0,0};
    f32x4 zf = {0.f,0.f,0.f,0.f};

    short8 qf = zero8;
    if (quad < 2)
        qf = *(const short8*)(Qb + ((size_t)lb * Nn + qbase + c15) * 16 + quad * 8);

    const unsigned short* Kbase = Kb + ((size_t)lb * Nn + c15) * 16 + quad * 8;
    const unsigned short* Vbase = Vt + (size_t)lb * (Dd * Nn) + c15 * Nn + quad * 8;

    f32x4 ot = zf;
    float rs = 0.f;

    for (int c8 = 0; c8 < 8; ++c8) {
        const int kb = c8 * 128;
        f32x4 st[8];
#pragma unroll
        for (int kt = 0; kt < 8; ++kt) {
            short8 kf = zero8;
            if (quad < 2)
                kf = *(const short8*)(Kbase + (size_t)(kb + kt * 16) * 16);
            st[kt] = __builtin_amdgcn_mfma_f32_16x16x32_bf16(kf, qf, zf, 0, 0, 0);
        }
#pragma unroll
        for (int kt = 0; kt < 8; ++kt) {
            float p0 = EXP2(st[kt].x), p1 = EXP2(st[kt].y);
            float p2 = EXP2(st[kt].z), p3 = EXP2(st[kt].w);
            rs += (p0 + p1) + (p2 + p3);
            *(uint2*)(prow + kt * 16 + quad * 4) =
                make_uint2(pack2bf(p0, p1), pack2bf(p2, p3));
        }
#pragma unroll
        for (int g = 0; g < 4; ++g) {
            short8 pf = *(const short8*)(prow + g * 32 + quad * 8);
            short8 vf = *(const short8*)(Vbase + kb + g * 32);
            ot = __builtin_amdgcn_mfma_f32_16x16x32_bf16(vf, pf, ot, 0, 0, 0);
        }
    }
    rs += __shfl_xor(rs, 16);
    rs += __shfl_xor(rs, 32);
    const float inv = 1.f / rs;

    float* dst = Oa + ((size_t)lb * Nn + qbase + c15) * 16 + quad * 4;
    f32x4 res; res.x = ot.x*inv; res.y = ot.y*inv; res.z = ot.z*inv; res.w = ot.w*inv;
    *(f32x4*)dst = res;
}

// ---------------------------------------------------------------------------
// Epilogue: O = Q + Oa; O += relu(O@Wo^T+bo); head; Z + logdet
// grid (64, NL), 256 threads, 1 row/thread
// ---------------------------------------------------------------------------
__launch_bounds__(256)
__global__ void gf_epi(const float* __restrict__ X,
                       const float* __restrict__ Wq, const float* __restrict__ bq,
                       const float* __restrict__ Wo, const float* __restrict__ bo,
                       const float* __restrict__ Wf, const float* __restrict__ bf,
                       const float* __restrict__ Oa, float* __restrict__ out) {
    const int l = blockIdx.y, i = l + 1;
    const int rid = blockIdx.x * 256 + threadIdx.x;    // 0..Bb*Nn-1
    const int b = rid >> 10, n = rid & (Nn - 1);
    const float* wq = Wq + l * 256;  const float* bql = bq + l * 16;
    const float* wo = Wo + l * 256;  const float* bol = bo + l * 16;
    const float* wf = Wf + l * 32;   const float* bfl = bf + l * 2;

    float xr[16]; load_row16(X + ((size_t)b * Nn + n) * Dd, xr);
    float q[16];  project(xr, wq, bql, i, q);
    const float* oa = Oa + ((size_t)(l * Bb + b) * Nn + n) * 16;

    float a[16];
#pragma unroll
    for (int c = 0; c < 16; c++) a[c] = q[c] + oa[c];

    float tt[16];
#pragma unroll
    for (int r = 0; r < 16; r++) {
        float acc = bol[r];
#pragma unroll
        for (int c = 0; c < 16; c++) acc = fmaf(a[c], wo[r * 16 + c], acc);
        tt[r] = fmaxf(acc, 0.f);
    }
#pragma unroll
    for (int r = 0; r < 16; r++) a[r] += (r < i) ? tt[r] : 0.f;

    float mu = bfl[0], al = bfl[1];
#pragma unroll
    for (int c = 0; c < 16; c++) {
        mu = fmaf(a[c], wf[c], mu);
        al = fmaf(a[c], wf[16 + c], al);
    }
    out[((size_t)(b * Nn + n)) * Dd + i] = (xr[i] - mu) * __expf(-al);
    atomicAdd(out + (size_t)Bb * Nn * Dd + b * Nn + n, -al);
}

// ---------------------------------------------------------------------------
// Fallback (R1 fp32 kernel) if workspace is too small
// ---------------------------------------------------------------------------
__launch_bounds__(512, 2)
__global__ void gf_layer_fb(const float* __restrict__ X,
                            const float* __restrict__ Wq, const float* __restrict__ bq,
                            const float* __restrict__ Wk, const float* __restrict__ bk,
                            const float* __restrict__ Wv, const float* __restrict__ bv,
                            const float* __restrict__ Wo, const float* __restrict__ bo,
                            const float* __restrict__ Wf, const float* __restrict__ bf,
                            float* __restrict__ out) {
    const int l = blockIdx.x, b = blockIdx.y, i = l + 1, t = threadIdx.x;
    const float rscale = rsqrtf((float)i);
    __shared__ float Ksh[512 * 16];
    __shared__ float Vsh[512 * 16];
    const float* Xb = X + (size_t)b * Nn * Dd;
    const float* wq = Wq + l * 256; const float* wk = Wk + l * 256;
    const float* wv = Wv + l * 256; const float* wo = Wo + l * 256;
    const float* wf = Wf + l * 32;
    const float* bql = bq + l * 16; const float* bkl = bk + l * 16;
    const float* bvl = bv + l * 16; const float* bol = bo + l * 16;
    const float* bfl = bf + l * 2;
    const int n0 = t, n1 = t + 512;
    float q0[16], q1[16], xi0, xi1;
    {
        float xr[16];
        load_row16(Xb + (size_t)n0 * Dd, xr); xi0 = xr[i]; project(xr, wq, bql, i, q0);
        load_row16(Xb + (size_t)n1 * Dd, xr); xi1 = xr[i]; project(xr, wq, bql, i, q1);
    }
    float o0[16], o1[16];
#pragma unroll
    for (int c = 0; c < 16; c++) { o0[c] = 0.f; o1[c] = 0.f; }
    float ls0 = 0.f, ls1 = 0.f;
    for (int ch = 0; ch < 2; ch++) {
        float kr[16], vr[16];
        {
            float kx[16];
            load_row16(Xb + (size_t)(ch * 512 + t) * Dd, kx);
            project(kx, wk, bkl, i, kr);
            project(kx, wv, bvl, i, vr);
        }
        __syncthreads();
#pragma unroll
        for (int j = 0; j < 4; j++) {
            ((float4*)&Ksh[t * 16])[j] = ((float4*)kr)[j];
            ((float4*)&Vsh[t * 16])[j] = ((float4*)vr)[j];
        }
        __syncthreads();
        for (int k = 0; k < 512; k++) {
            float kk[16], vv[16];
#pragma unroll
            for (int j = 0; j < 4; j++) ((float4*)kk)[j] = ((const float4*)&Ksh[k * 16])[j];
            float s0 = 0.f, s1 = 0.f;
#pragma unroll
            for (int c = 0; c < 16; c++) { s0 = fmaf(q0[c], kk[c], s0); s1 = fmaf(q1[c], kk[c], s1); }
            float p0 = __expf(s0 * rscale), p1 = __expf(s1 * rscale);
            ls0 += p0; ls1 += p1;
#pragma unroll
            for (int j = 0; j < 4; j++) ((float4*)vv)[j] = ((const float4*)&Vsh[k * 16])[j];
#pragma unroll
            for (int c = 0; c < 16; c++) { o0[c] = fmaf(p0, vv[c], o0[c]); o1[c] = fmaf(p1, vv[c], o1[c]); }
        }
        __syncthreads();
    }
    float* logdet = out + (size_t)Bb * Nn * Dd;
#pragma unroll
    for (int rowsel = 0; rowsel < 2; rowsel++) {
        const float* qr = rowsel ? q1 : q0; const float* orr = rowsel ? o1 : o0;
        float lsum = rowsel ? ls1 : ls0; float xin = rowsel ? xi1 : xi0;
        int n = rowsel ? n1 : n0;
        float a[16]; float inv = 1.f / lsum;
#pragma unroll
        for (int c = 0; c < 16; c++) a[c] = qr[c] + orr[c] * inv;
        float tt[16];
#pragma unroll
        for (int r = 0; r < 16; r++) {
            float acc = bol[r];
#pragma unroll
            for (int c = 0; c < 16; c++) acc = fmaf(a[c], wo[r * 16 + c], acc);
            tt[r] = fmaxf(acc, 0.f);
        }
#pragma unroll
        for (int r = 0; r < 16; r++) a[r] += (r < i) ? tt[r] : 0.f;
        float mu = bfl[0], al = bfl[1];
#pragma unroll
        for (int c = 0; c < 16; c++) { mu = fmaf(a[c], wf[c], mu); al = fmaf(a[c], wf[16 + c], al); }
        out[((size_t)(b * Nn + n)) * Dd + i] = (xin - mu) * __expf(-al);
        atomicAdd(logdet + b * Nn + n, -al);
    }
}

extern "C" void kernel_launch(void* const* d_in, const int* in_sizes, int n_in,
                              void* d_out, int out_size, void* d_ws, size_t ws_size,
                              hipStream_t stream) {
    const float* X  = (const float*)d_in[0];
    const float* ip = (const float*)d_in[1];
    const float* Wq = (const float*)d_in[2];
    const float* bq = (const float*)d_in[3];
    const float* Wk = (const float*)d_in[4];
    const float* bk = (const float*)d_in[5];
    const float* Wv = (const float*)d_in[6];
    const float* bv = (const float*)d_in[7];
    const float* Wo = (const float*)d_in[8];
    const float* bo = (const float*)d_in[9];
    const float* Wf = (const float*)d_in[10];
    const float* bf = (const float*)d_in[11];
    float* out = (float*)d_out;

    const size_t nBF  = (size_t)NL * Bb * Nn * 16;        // 3,932,160 elems
    const size_t need = 3 * nBF * 2 + nBF * 4;            // Qb+Kb+Vt + Oa = 39.3MB

    gf_init<<<(Bb * Nn + 255) / 256, 256, 0, stream>>>(X, ip, out);

    if (ws_size < need) {   // defensive fallback: R1 fp32 path
        gf_layer_fb<<<dim3(NL, Bb), 512, 0, stream>>>(X, Wq, bq, Wk, bk, Wv, bv,
                                                      Wo, bo, Wf, bf, out);
        return;
    }

    unsigned short* Qb = (unsigned short*)d_ws;
    unsigned short* Kb = Qb + nBF;
    unsigned short* Vt = Kb + nBF;
    float*          Oa = (float*)(Vt + nBF);

    gf_proj<<<dim3(NL, Bb), 256, 0, stream>>>(X, Wq, bq, Wk, bk, Wv, bv, Qb, Kb, Vt);
    gf_attn<<<dim3(16, NL, Bb), 256, 0, stream>>>(Qb, Kb, Vt, Oa);
    gf_epi<<<dim3(64, NL), 256, 0, stream>>>(X, Wq, bq, Wo, bo, Wf, bf, Oa, out);
}

// Round 3
// 158.357 us; speedup vs baseline: 2.1950x; 1.5825x over previous
//
#include <hip/hip_runtime.h>
#include <math.h>

#define Bb 16
#define Nn 1024
#define Dd 16
#define NL 15

typedef __attribute__((ext_vector_type(8))) short short8;
typedef __attribute__((ext_vector_type(4))) float f32x4;

#if __has_builtin(__builtin_amdgcn_exp2f)
#define EXP2(x) __builtin_amdgcn_exp2f(x)
#else
#define EXP2(x) exp2f(x)
#endif

// LDS layout (dynamic, 147712 B total):
//   K   : [1024 keys][16 shorts]            32768 B   (rows 32B, b128-friendly)
//   V^T : [16 d][1032 shorts]               33024 B   (padded: 16-way -> 2-way)
//   P   : 16 waves x [64 rows][40 shorts]   81920 B   (80B rows; reused as
//         Qtmp (bf16), P (bf16), O (fp32 stride-20) -- all wave-local)
#define PROW 40
#define WREG (64 * PROW * 2)                 // 5120 B per wave
#define V_OFF (Nn * 16 * 2)                  // 32768
#define VSTR 1032
#define P_OFF (V_OFF + Dd * VSTR * 2)        // 65792
#define LDS_TOTAL (P_OFF + 16 * WREG)        // 147712

// round-half-up fp32->bf16 (values are small/finite; <=1ulp, no tie bias issues)
__device__ __forceinline__ unsigned pack2bf(float a, float b) {
    unsigned ua = __float_as_uint(a) + 0x8000u;
    unsigned ub = __float_as_uint(b) + 0x8000u;
    return (ua >> 16) | (ub & 0xffff0000u);
}
__device__ __forceinline__ unsigned short bf1(float a) {
    return (unsigned short)((__float_as_uint(a) + 0x8000u) >> 16);
}

__device__ __forceinline__ void project(const float* __restrict__ xrow,
                                        const float* __restrict__ W,
                                        const float* __restrict__ bias,
                                        int i, float* __restrict__ q) {
#pragma unroll
    for (int r = 0; r < 16; r++) q[r] = 0.f;
    for (int c = 0; c < i; c++) {
        float xc = xrow[c];
#pragma unroll
        for (int r = 0; r < 16; r++) q[r] = fmaf(xc, W[r * 16 + c], q[r]);
    }
#pragma unroll
    for (int r = 0; r < 16; r++) q[r] = (r < i) ? (q[r] + bias[r]) : 0.f;
}

__device__ __forceinline__ void load_row16(const float* __restrict__ p, float* __restrict__ x) {
    const float4* xp = (const float4*)p;
    float4 a = xp[0], b = xp[1], c = xp[2], d = xp[3];
    x[0]=a.x; x[1]=a.y; x[2]=a.z; x[3]=a.w;
    x[4]=b.x; x[5]=b.y; x[6]=b.z; x[7]=b.w;
    x[8]=c.x; x[9]=c.y; x[10]=c.z; x[11]=c.w;
    x[12]=d.x; x[13]=d.y; x[14]=d.z; x[15]=d.w;
}

// ---------------------------------------------------------------------------
// Layer 0
// ---------------------------------------------------------------------------
__global__ void gf_init(const float* __restrict__ X, const float* __restrict__ ip,
                        float* __restrict__ out) {
    int idx = blockIdx.x * blockDim.x + threadIdx.x;
    if (idx >= Bb * Nn) return;
    float mu = ip[0], alpha = ip[1];
    float x0 = X[(size_t)idx * Dd];
    out[(size_t)idx * Dd] = (x0 - mu) * __expf(-alpha);
    out[(size_t)Bb * Nn * Dd + idx] = -alpha;
}

// ---------------------------------------------------------------------------
// Fused: proj -> barrier -> per-wave flash attn (MFMA) -> wave-local epilogue
// grid (NL, Bb), 1024 threads (16 waves, 64 queries/wave), 1 block/CU.
// ---------------------------------------------------------------------------
__launch_bounds__(1024, 4)
__global__ void gf_fused(const float* __restrict__ X,
                         const float* __restrict__ Wq, const float* __restrict__ bq,
                         const float* __restrict__ Wk, const float* __restrict__ bk,
                         const float* __restrict__ Wv, const float* __restrict__ bv,
                         const float* __restrict__ Wo, const float* __restrict__ bo,
                         const float* __restrict__ Wf, const float* __restrict__ bf,
                         float* __restrict__ out) {
    extern __shared__ char smem[];
    const int l = blockIdx.x, b = blockIdx.y, i = l + 1;
    const int t = threadIdx.x;
    const int wid = t >> 6, lane = t & 63;
    const int c15 = lane & 15, quad = lane >> 4;
    const float qscale = 1.4426950408889634f * rsqrtf((float)i);

    unsigned short* Ksh = (unsigned short*)smem;
    unsigned short* Vsh = (unsigned short*)(smem + V_OFF);
    unsigned short* Pw  = (unsigned short*)(smem + P_OFF + wid * WREG);

    const float* Xb  = X  + (size_t)b * Nn * Dd;
    const float* wq  = Wq + l * 256;  const float* bql = bq + l * 16;
    const float* wk  = Wk + l * 256;  const float* bkl = bk + l * 16;
    const float* wvp = Wv + l * 256;  const float* bvl = bv + l * 16;
    const float* wo  = Wo + l * 256;  const float* bol = bo + l * 16;
    const float* wf  = Wf + l * 32;   const float* bfl = bf + l * 2;

    // ---------------- proj phase: thread t = row n = t ----------------
    {
        float xr[16]; load_row16(Xb + (size_t)t * Dd, xr);
        float tmp[16];
        unsigned u[8];

        project(xr, wk, bkl, i, tmp);
#pragma unroll
        for (int r = 0; r < 8; r++) u[r] = pack2bf(tmp[2*r], tmp[2*r+1]);
        {
            uint4* kd = (uint4*)(Ksh + t * 16);
            kd[0] = make_uint4(u[0], u[1], u[2], u[3]);
            kd[1] = make_uint4(u[4], u[5], u[6], u[7]);
        }

        project(xr, wvp, bvl, i, tmp);
#pragma unroll
        for (int d = 0; d < 16; d++) Vsh[d * VSTR + t] = bf1(tmp[d]);

        project(xr, wq, bql, i, tmp);
#pragma unroll
        for (int r = 0; r < 8; r++) u[r] = pack2bf(tmp[2*r] * qscale, tmp[2*r+1] * qscale);
        {
            uint4* qd = (uint4*)(Pw + lane * PROW);
            qd[0] = make_uint4(u[0], u[1], u[2], u[3]);
            qd[1] = make_uint4(u[4], u[5], u[6], u[7]);
        }
    }
    __syncthreads();

    // ---------------- attention phase: wave -> queries wid*64 .. +63 ----------
    short8 zr = {0,0,0,0,0,0,0,0};
    f32x4 zf = {0.f,0.f,0.f,0.f};

    short8 qf[4];
#pragma unroll
    for (int f = 0; f < 4; f++)
        qf[f] = (quad < 2) ? *(const short8*)(Pw + (f*16 + c15) * PROW + quad * 8) : zr;

    f32x4 ot[4] = {zf, zf, zf, zf};
    float rs[4] = {0.f, 0.f, 0.f, 0.f};

    const unsigned short* Kp = Ksh + (size_t)c15 * 16 + quad * 8;
    const unsigned short* Vp = Vsh + (size_t)c15 * VSTR + quad * 8;

    for (int kb = 0; kb < Nn; kb += 32) {
        short8 kf[2];
#pragma unroll
        for (int kt = 0; kt < 2; kt++)
            kf[kt] = (quad < 2) ? *(const short8*)(Kp + (size_t)(kb + kt*16) * 16) : zr;

        f32x4 st[2][4];
#pragma unroll
        for (int kt = 0; kt < 2; kt++)
#pragma unroll
            for (int f = 0; f < 4; f++)
                st[kt][f] = __builtin_amdgcn_mfma_f32_16x16x32_bf16(kf[kt], qf[f], zf, 0, 0, 0);

#pragma unroll
        for (int kt = 0; kt < 2; kt++)
#pragma unroll
            for (int f = 0; f < 4; f++) {
                float p0 = EXP2(st[kt][f].x), p1 = EXP2(st[kt][f].y);
                float p2 = EXP2(st[kt][f].z), p3 = EXP2(st[kt][f].w);
                rs[f] += (p0 + p1) + (p2 + p3);
                *(uint2*)(Pw + (f*16 + c15) * PROW + kt*16 + quad*4) =
                    make_uint2(pack2bf(p0, p1), pack2bf(p2, p3));
            }

        short8 vf = *(const short8*)(Vp + kb);
#pragma unroll
        for (int f = 0; f < 4; f++) {
            short8 pf = *(const short8*)(Pw + (f*16 + c15) * PROW + quad * 8);
            ot[f] = __builtin_amdgcn_mfma_f32_16x16x32_bf16(vf, pf, ot[f], 0, 0, 0);
        }
    }

    // normalize, stash O (fp32, stride-20 rows) in the same wave-local region
    float* Ow = (float*)Pw;
#pragma unroll
    for (int f = 0; f < 4; f++) {
        float r = rs[f];
        r += __shfl_xor(r, 16);
        r += __shfl_xor(r, 32);
        float inv = 1.f / r;
        f32x4 res;
        res.x = ot[f].x * inv; res.y = ot[f].y * inv;
        res.z = ot[f].z * inv; res.w = ot[f].w * inv;
        *(f32x4*)(Ow + (f*16 + c15) * 20 + quad * 4) = res;
    }

    // ---------------- epilogue (wave-local; thread t = query n = t) ----------
    {
        float xr[16]; load_row16(Xb + (size_t)t * Dd, xr);
        float q[16];  project(xr, wq, bql, i, q);
        const float* orow = (const float*)(smem + P_OFF + wid * WREG) + lane * 20;

        float a[16];
#pragma unroll
        for (int c = 0; c < 16; c++) a[c] = q[c] + orow[c];

        float tt[16];
#pragma unroll
        for (int r = 0; r < 16; r++) {
            float acc = bol[r];
#pragma unroll
            for (int c = 0; c < 16; c++) acc = fmaf(a[c], wo[r * 16 + c], acc);
            tt[r] = fmaxf(acc, 0.f);
        }
#pragma unroll
        for (int r = 0; r < 16; r++) a[r] += (r < i) ? tt[r] : 0.f;

        float mu = bfl[0], al = bfl[1];
#pragma unroll
        for (int c = 0; c < 16; c++) {
            mu = fmaf(a[c], wf[c], mu);
            al = fmaf(a[c], wf[16 + c], al);
        }
        out[((size_t)(b * Nn + t)) * Dd + i] = (xr[i] - mu) * __expf(-al);
        atomicAdd(out + (size_t)Bb * Nn * Dd + b * Nn + t, -al);
    }
}

// ---------------------------------------------------------------------------
// Fallback (R1 fp32 kernel) if large dynamic LDS is unavailable
// ---------------------------------------------------------------------------
__launch_bounds__(512, 2)
__global__ void gf_layer_fb(const float* __restrict__ X,
                            const float* __restrict__ Wq, const float* __restrict__ bq,
                            const float* __restrict__ Wk, const float* __restrict__ bk,
                            const float* __restrict__ Wv, const float* __restrict__ bv,
                            const float* __restrict__ Wo, const float* __restrict__ bo,
                            const float* __restrict__ Wf, const float* __restrict__ bf,
                            float* __restrict__ out) {
    const int l = blockIdx.x, b = blockIdx.y, i = l + 1, t = threadIdx.x;
    const float rscale = rsqrtf((float)i);
    __shared__ float Ksh[512 * 16];
    __shared__ float Vsh[512 * 16];
    const float* Xb = X + (size_t)b * Nn * Dd;
    const float* wq = Wq + l * 256; const float* wk = Wk + l * 256;
    const float* wv = Wv + l * 256; const float* wo = Wo + l * 256;
    const float* wf = Wf + l * 32;
    const float* bql = bq + l * 16; const float* bkl = bk + l * 16;
    const float* bvl = bv + l * 16; const float* bol = bo + l * 16;
    const float* bfl = bf + l * 2;
    const int n0 = t, n1 = t + 512;
    float q0[16], q1[16], xi0, xi1;
    {
        float xr[16];
        load_row16(Xb + (size_t)n0 * Dd, xr); xi0 = xr[i]; project(xr, wq, bql, i, q0);
        load_row16(Xb + (size_t)n1 * Dd, xr); xi1 = xr[i]; project(xr, wq, bql, i, q1);
    }
    float o0[16], o1[16];
#pragma unroll
    for (int c = 0; c < 16; c++) { o0[c] = 0.f; o1[c] = 0.f; }
    float ls0 = 0.f, ls1 = 0.f;
    for (int ch = 0; ch < 2; ch++) {
        float kr[16], vr[16];
        {
            float kx[16];
            load_row16(Xb + (size_t)(ch * 512 + t) * Dd, kx);
            project(kx, wk, bkl, i, kr);
            project(kx, wv, bvl, i, vr);
        }
        __syncthreads();
#pragma unroll
        for (int j = 0; j < 4; j++) {
            ((float4*)&Ksh[t * 16])[j] = ((float4*)kr)[j];
            ((float4*)&Vsh[t * 16])[j] = ((float4*)vr)[j];
        }
        __syncthreads();
        for (int k = 0; k < 512; k++) {
            float kk[16], vv[16];
#pragma unroll
            for (int j = 0; j < 4; j++) ((float4*)kk)[j] = ((const float4*)&Ksh[k * 16])[j];
            float s0 = 0.f, s1 = 0.f;
#pragma unroll
            for (int c = 0; c < 16; c++) { s0 = fmaf(q0[c], kk[c], s0); s1 = fmaf(q1[c], kk[c], s1); }
            float p0 = __expf(s0 * rscale), p1 = __expf(s1 * rscale);
            ls0 += p0; ls1 += p1;
#pragma unroll
            for (int j = 0; j < 4; j++) ((float4*)vv)[j] = ((const float4*)&Vsh[k * 16])[j];
#pragma unroll
            for (int c = 0; c < 16; c++) { o0[c] = fmaf(p0, vv[c], o0[c]); o1[c] = fmaf(p1, vv[c], o1[c]); }
        }
        __syncthreads();
    }
    float* logdet = out + (size_t)Bb * Nn * Dd;
#pragma unroll
    for (int rowsel = 0; rowsel < 2; rowsel++) {
        const float* qr = rowsel ? q1 : q0; const float* orr = rowsel ? o1 : o0;
        float lsum = rowsel ? ls1 : ls0; float xin = rowsel ? xi1 : xi0;
        int n = rowsel ? n1 : n0;
        float a[16]; float inv = 1.f / lsum;
#pragma unroll
        for (int c = 0; c < 16; c++) a[c] = qr[c] + orr[c] * inv;
        float tt[16];
#pragma unroll
        for (int r = 0; r < 16; r++) {
            float acc = bol[r];
#pragma unroll
            for (int c = 0; c < 16; c++) acc = fmaf(a[c], wo[r * 16 + c], acc);
            tt[r] = fmaxf(acc, 0.f);
        }
#pragma unroll
        for (int r = 0; r < 16; r++) a[r] += (r < i) ? tt[r] : 0.f;
        float mu = bfl[0], al = bfl[1];
#pragma unroll
        for (int c = 0; c < 16; c++) { mu = fmaf(a[c], wf[c], mu); al = fmaf(a[c], wf[16 + c], al); }
        out[((size_t)(b * Nn + n)) * Dd + i] = (xin - mu) * __expf(-al);
        atomicAdd(logdet + b * Nn + n, -al);
    }
}

extern "C" void kernel_launch(void* const* d_in, const int* in_sizes, int n_in,
                              void* d_out, int out_size, void* d_ws, size_t ws_size,
                              hipStream_t stream) {
    const float* X  = (const float*)d_in[0];
    const float* ip = (const float*)d_in[1];
    const float* Wq = (const float*)d_in[2];
    const float* bq = (const float*)d_in[3];
    const float* Wk = (const float*)d_in[4];
    const float* bk = (const float*)d_in[5];
    const float* Wv = (const float*)d_in[6];
    const float* bv = (const float*)d_in[7];
    const float* Wo = (const float*)d_in[8];
    const float* bo = (const float*)d_in[9];
    const float* Wf = (const float*)d_in[10];
    const float* bf = (const float*)d_in[11];
    float* out = (float*)d_out;

    gf_init<<<(Bb * Nn + 255) / 256, 256, 0, stream>>>(X, ip, out);

    hipError_t e = hipFuncSetAttribute((const void*)gf_fused,
                                       hipFuncAttributeMaxDynamicSharedMemorySize,
                                       LDS_TOTAL);
    if (e == hipSuccess) {
        gf_fused<<<dim3(NL, Bb), 1024, LDS_TOTAL, stream>>>(
            X, Wq, bq, Wk, bk, Wv, bv, Wo, bo, Wf, bf, out);
    } else {
        gf_layer_fb<<<dim3(NL, Bb), 512, 0, stream>>>(
            X, Wq, bq, Wk, bk, Wv, bv, Wo, bo, Wf, bf, out);
    }
}

// Round 4
// 156.325 us; speedup vs baseline: 2.2235x; 1.0130x over previous
//
#include <hip/hip_runtime.h>
#include <math.h>

#define Bb 16
#define Nn 1024
#define Dd 16
#define NL 15

typedef __attribute__((ext_vector_type(8))) short short8;
typedef __attribute__((ext_vector_type(4))) float f32x4;
typedef __attribute__((ext_vector_type(16))) float f32x16;

#if __has_builtin(__builtin_amdgcn_exp2f)
#define EXP2(x) __builtin_amdgcn_exp2f(x)
#else
#define EXP2(x) exp2f(x)
#endif

// LDS layout (dynamic, 147968 B):
//   K   : [1024 keys][16 shorts]  (32 B rows, dense)        32768 B
//   V^T : [16 d][VSTR=1040 shorts] (pad: uniform banks)     33280 B
//   P   : 16 waves x [64 rows][40 shorts] (80 B rows; reused as Q-stage bf16,
//         P bf16, O fp32 stride-20 — all wave-local)        81920 B
#define VSTR 1040
#define PSTR 40
#define WREG (64 * PSTR * 2)                 // 5120 B / wave
#define V_OFF (Nn * Dd * 2)                  // 32768
#define P_OFF (V_OFF + Dd * VSTR * 2)        // 66048
#define LDS_TOTAL (P_OFF + 16 * WREG)        // 147968

// round-half-up fp32->bf16 (positive/small finite values here)
__device__ __forceinline__ unsigned pack2bf(float a, float b) {
    unsigned ua = __float_as_uint(a) + 0x8000u;
    unsigned ub = __float_as_uint(b) + 0x8000u;
    return (ua >> 16) | (ub & 0xffff0000u);
}
__device__ __forceinline__ unsigned short bf1(float a) {
    return (unsigned short)((__float_as_uint(a) + 0x8000u) >> 16);
}

__device__ __forceinline__ void project(const float* __restrict__ xrow,
                                        const float* __restrict__ W,
                                        const float* __restrict__ bias,
                                        int i, float* __restrict__ q) {
#pragma unroll
    for (int r = 0; r < 16; r++) q[r] = 0.f;
    for (int c = 0; c < i; c++) {
        float xc = xrow[c];
#pragma unroll
        for (int r = 0; r < 16; r++) q[r] = fmaf(xc, W[r * 16 + c], q[r]);
    }
#pragma unroll
    for (int r = 0; r < 16; r++) q[r] = (r < i) ? (q[r] + bias[r]) : 0.f;
}

__device__ __forceinline__ void load_row16(const float* __restrict__ p, float* __restrict__ x) {
    const float4* xp = (const float4*)p;
    float4 a = xp[0], b = xp[1], c = xp[2], d = xp[3];
    x[0]=a.x; x[1]=a.y; x[2]=a.z; x[3]=a.w;
    x[4]=b.x; x[5]=b.y; x[6]=b.z; x[7]=b.w;
    x[8]=c.x; x[9]=c.y; x[10]=c.z; x[11]=c.w;
    x[12]=d.x; x[13]=d.y; x[14]=d.z; x[15]=d.w;
}

// ---------------------------------------------------------------------------
// Fused: proj -> barrier -> per-wave flash attn (32x32x16 QK, 16x16x32 PV)
// grid (NL, Bb), 1024 threads (16 waves, 64 queries/wave). Writes Z col i and
// per-layer alpha to ws (no atomics).
// ---------------------------------------------------------------------------
__launch_bounds__(1024, 4)
__global__ void gf_fused(const float* __restrict__ X,
                         const float* __restrict__ Wq, const float* __restrict__ bq,
                         const float* __restrict__ Wk, const float* __restrict__ bk,
                         const float* __restrict__ Wv, const float* __restrict__ bv,
                         const float* __restrict__ Wo, const float* __restrict__ bo,
                         const float* __restrict__ Wf, const float* __restrict__ bf,
                         float* __restrict__ als, float* __restrict__ out) {
    extern __shared__ char smem[];
    const int l = blockIdx.x, b = blockIdx.y, i = l + 1;
    const int t = threadIdx.x;
    const int wid = t >> 6, lane = t & 63;
    const int c15 = lane & 15, quad = lane >> 4;
    const int q31 = lane & 31, h = lane >> 5;
    const float qscale = 1.4426950408889634f * rsqrtf((float)i);

    unsigned short* Ksh = (unsigned short*)smem;
    unsigned short* Vsh = (unsigned short*)(smem + V_OFF);
    unsigned short* Pw  = (unsigned short*)(smem + P_OFF + wid * WREG);

    const float* Xb  = X  + (size_t)b * Nn * Dd;
    const float* wq  = Wq + l * 256;  const float* bql = bq + l * 16;
    const float* wk  = Wk + l * 256;  const float* bkl = bk + l * 16;
    const float* wvp = Wv + l * 256;  const float* bvl = bv + l * 16;
    const float* wo  = Wo + l * 256;  const float* bol = bo + l * 16;
    const float* wf  = Wf + l * 32;   const float* bfl = bf + l * 2;

    // ---------------- proj phase: thread t = row n = t ----------------
    {
        float xr[16]; load_row16(Xb + (size_t)t * Dd, xr);
        float tmp[16];
        unsigned u[8];

        project(xr, wk, bkl, i, tmp);
#pragma unroll
        for (int r = 0; r < 8; r++) u[r] = pack2bf(tmp[2*r], tmp[2*r+1]);
        {
            uint4* kd = (uint4*)(Ksh + t * 16);
            kd[0] = make_uint4(u[0], u[1], u[2], u[3]);
            kd[1] = make_uint4(u[4], u[5], u[6], u[7]);
        }

        project(xr, wvp, bvl, i, tmp);
#pragma unroll
        for (int d = 0; d < 16; d++) Vsh[d * VSTR + t] = bf1(tmp[d]);

        project(xr, wq, bql, i, tmp);
#pragma unroll
        for (int r = 0; r < 8; r++) u[r] = pack2bf(tmp[2*r] * qscale, tmp[2*r+1] * qscale);
        {
            uint4* qd = (uint4*)(Pw + lane * PSTR);
            qd[0] = make_uint4(u[0], u[1], u[2], u[3]);
            qd[1] = make_uint4(u[4], u[5], u[6], u[7]);
        }
    }
    __syncthreads();

    // ---------------- attention: wave -> queries wid*64..+63 ----------------
    f32x16 zf16 = {};
    f32x4  zf4  = {};

    // Q B-frags (32x32x16): B[n=q31 + 32*ft][k = 8h + j]
    short8 qf[2];
    qf[0] = *(const short8*)(Pw + q31        * PSTR + h * 8);
    qf[1] = *(const short8*)(Pw + (32 + q31) * PSTR + h * 8);

    const unsigned short* Kp = Ksh + (size_t)q31 * 16 + h * 8;   // A: K[key][8h+j]
    const unsigned short* Vp = Vsh + (size_t)c15 * VSTR + quad * 8;

    f32x4 ot[4] = {zf4, zf4, zf4, zf4};
    float rs[2] = {0.f, 0.f};

    short8 kf = *(const short8*)(Kp);
    short8 vf = *(const short8*)(Vp);

    for (int kb = 0; kb < Nn; kb += 32) {
        const int kn = (kb + 32) & (Nn - 1);
        short8 kfn = *(const short8*)(Kp + (size_t)kn * 16);
        short8 vfn = *(const short8*)(Vp + kn);

        f32x16 st0 = __builtin_amdgcn_mfma_f32_32x32x16_bf16(kf, qf[0], zf16, 0, 0, 0);
        f32x16 st1 = __builtin_amdgcn_mfma_f32_32x32x16_bf16(kf, qf[1], zf16, 0, 0, 0);

        // lane holds keys {8g+4h+0..3} (g=0..3) for query q31 (+32*ft)
        unsigned short* pw0 = Pw + q31 * PSTR + 4 * h;
#pragma unroll
        for (int g = 0; g < 4; g++) {
            float e0 = EXP2(st0[4*g+0]), e1 = EXP2(st0[4*g+1]);
            float e2 = EXP2(st0[4*g+2]), e3 = EXP2(st0[4*g+3]);
            rs[0] += (e0 + e1) + (e2 + e3);
            *(uint2*)(pw0 + 8*g) = make_uint2(pack2bf(e0, e1), pack2bf(e2, e3));
        }
        unsigned short* pw1 = pw0 + 32 * PSTR;
#pragma unroll
        for (int g = 0; g < 4; g++) {
            float e0 = EXP2(st1[4*g+0]), e1 = EXP2(st1[4*g+1]);
            float e2 = EXP2(st1[4*g+2]), e3 = EXP2(st1[4*g+3]);
            rs[1] += (e0 + e1) + (e2 + e3);
            *(uint2*)(pw1 + 8*g) = make_uint2(pack2bf(e0, e1), pack2bf(e2, e3));
        }

        // PV: A=V^T[d=c15][k=quad*8+j], B=P[q=f*16+c15][k=quad*8+j]
#pragma unroll
        for (int f = 0; f < 4; f++) {
            short8 pf = *(const short8*)(Pw + (f*16 + c15) * PSTR + quad * 8);
            ot[f] = __builtin_amdgcn_mfma_f32_16x16x32_bf16(vf, pf, ot[f], 0, 0, 0);
        }
        kf = kfn; vf = vfn;
    }

    rs[0] += __shfl_xor(rs[0], 32);
    rs[1] += __shfl_xor(rs[1], 32);
    const float iv0 = 1.f / rs[0];
    const float iv1 = 1.f / rs[1];

    // normalize + stash O rows (fp32, stride-20) in wave-local region
    float* Ow = (float*)Pw;
#pragma unroll
    for (int f = 0; f < 4; f++) {
        float iv = __shfl((f & 2) ? iv1 : iv0, (f & 1) * 16 + c15);
        f32x4 res;
        res.x = ot[f].x * iv; res.y = ot[f].y * iv;
        res.z = ot[f].z * iv; res.w = ot[f].w * iv;
        *(f32x4*)(Ow + (f*16 + c15) * 20 + quad * 4) = res;
    }

    // ---------------- epilogue (wave-local; thread t = query n = t) ----------
    {
        float xr[16]; load_row16(Xb + (size_t)t * Dd, xr);
        float q[16];  project(xr, wq, bql, i, q);
        const float* orow = (const float*)(smem + P_OFF + wid * WREG) + lane * 20;

        float a[16];
#pragma unroll
        for (int c = 0; c < 16; c++) a[c] = q[c] + orow[c];

        float tt[16];
#pragma unroll
        for (int r = 0; r < 16; r++) {
            float acc = bol[r];
#pragma unroll
            for (int c = 0; c < 16; c++) acc = fmaf(a[c], wo[r * 16 + c], acc);
            tt[r] = fmaxf(acc, 0.f);
        }
#pragma unroll
        for (int r = 0; r < 16; r++) a[r] += (r < i) ? tt[r] : 0.f;

        float mu = bfl[0], al = bfl[1];
#pragma unroll
        for (int c = 0; c < 16; c++) {
            mu = fmaf(a[c], wf[c], mu);
            al = fmaf(a[c], wf[16 + c], al);
        }
        out[((size_t)(b * Nn + t)) * Dd + i] = (xr[i] - mu) * __expf(-al);
        als[(size_t)l * (Bb * Nn) + b * Nn + t] = al;
    }
}

// ---------------------------------------------------------------------------
// Final: layer-0 Z + logdet = -(alpha0 + sum_l al)   (no atomics)
// ---------------------------------------------------------------------------
__launch_bounds__(1024)
__global__ void gf_final(const float* __restrict__ X, const float* __restrict__ ip,
                         const float* __restrict__ als, float* __restrict__ out) {
    const int idx = blockIdx.x * 1024 + threadIdx.x;     // 0..Bb*Nn-1
    const float mu = ip[0], a0 = ip[1];
    float x0 = X[(size_t)idx * Dd];
    out[(size_t)idx * Dd] = (x0 - mu) * __expf(-a0);
    float ld = -a0;
#pragma unroll
    for (int l = 0; l < NL; l++) ld -= als[(size_t)l * (Bb * Nn) + idx];
    out[(size_t)Bb * Nn * Dd + idx] = ld;
}

// ---------------------------------------------------------------------------
// Fallback path (R1): init + fp32 kernel, if big dynamic LDS / ws unavailable
// ---------------------------------------------------------------------------
__global__ void gf_init(const float* __restrict__ X, const float* __restrict__ ip,
                        float* __restrict__ out) {
    int idx = blockIdx.x * blockDim.x + threadIdx.x;
    if (idx >= Bb * Nn) return;
    float mu = ip[0], alpha = ip[1];
    float x0 = X[(size_t)idx * Dd];
    out[(size_t)idx * Dd] = (x0 - mu) * __expf(-alpha);
    out[(size_t)Bb * Nn * Dd + idx] = -alpha;
}

__launch_bounds__(512, 2)
__global__ void gf_layer_fb(const float* __restrict__ X,
                            const float* __restrict__ Wq, const float* __restrict__ bq,
                            const float* __restrict__ Wk, const float* __restrict__ bk,
                            const float* __restrict__ Wv, const float* __restrict__ bv,
                            const float* __restrict__ Wo, const float* __restrict__ bo,
                            const float* __restrict__ Wf, const float* __restrict__ bf,
                            float* __restrict__ out) {
    const int l = blockIdx.x, b = blockIdx.y, i = l + 1, t = threadIdx.x;
    const float rscale = rsqrtf((float)i);
    __shared__ float Ksh[512 * 16];
    __shared__ float Vsh[512 * 16];
    const float* Xb = X + (size_t)b * Nn * Dd;
    const float* wq = Wq + l * 256; const float* wk = Wk + l * 256;
    const float* wv = Wv + l * 256; const float* wo = Wo + l * 256;
    const float* wf = Wf + l * 32;
    const float* bql = bq + l * 16; const float* bkl = bk + l * 16;
    const float* bvl = bv + l * 16; const float* bol = bo + l * 16;
    const float* bfl = bf + l * 2;
    const int n0 = t, n1 = t + 512;
    float q0[16], q1[16], xi0, xi1;
    {
        float xr[16];
        load_row16(Xb + (size_t)n0 * Dd, xr); xi0 = xr[i]; project(xr, wq, bql, i, q0);
        load_row16(Xb + (size_t)n1 * Dd, xr); xi1 = xr[i]; project(xr, wq, bql, i, q1);
    }
    float o0[16], o1[16];
#pragma unroll
    for (int c = 0; c < 16; c++) { o0[c] = 0.f; o1[c] = 0.f; }
    float ls0 = 0.f, ls1 = 0.f;
    for (int ch = 0; ch < 2; ch++) {
        float kr[16], vr[16];
        {
            float kx[16];
            load_row16(Xb + (size_t)(ch * 512 + t) * Dd, kx);
            project(kx, wk, bkl, i, kr);
            project(kx, wv, bvl, i, vr);
        }
        __syncthreads();
#pragma unroll
        for (int j = 0; j < 4; j++) {
            ((float4*)&Ksh[t * 16])[j] = ((float4*)kr)[j];
            ((float4*)&Vsh[t * 16])[j] = ((float4*)vr)[j];
        }
        __syncthreads();
        for (int k = 0; k < 512; k++) {
            float kk[16], vv[16];
#pragma unroll
            for (int j = 0; j < 4; j++) ((float4*)kk)[j] = ((const float4*)&Ksh[k * 16])[j];
            float s0 = 0.f, s1 = 0.f;
#pragma unroll
            for (int c = 0; c < 16; c++) { s0 = fmaf(q0[c], kk[c], s0); s1 = fmaf(q1[c], kk[c], s1); }
            float p0 = __expf(s0 * rscale), p1 = __expf(s1 * rscale);
            ls0 += p0; ls1 += p1;
#pragma unroll
            for (int j = 0; j < 4; j++) ((float4*)vv)[j] = ((const float4*)&Vsh[k * 16])[j];
#pragma unroll
            for (int c = 0; c < 16; c++) { o0[c] = fmaf(p0, vv[c], o0[c]); o1[c] = fmaf(p1, vv[c], o1[c]); }
        }
        __syncthreads();
    }
    float* logdet = out + (size_t)Bb * Nn * Dd;
#pragma unroll
    for (int rowsel = 0; rowsel < 2; rowsel++) {
        const float* qr = rowsel ? q1 : q0; const float* orr = rowsel ? o1 : o0;
        float lsum = rowsel ? ls1 : ls0; float xin = rowsel ? xi1 : xi0;
        int n = rowsel ? n1 : n0;
        float a[16]; float inv = 1.f / lsum;
#pragma unroll
        for (int c = 0; c < 16; c++) a[c] = qr[c] + orr[c] * inv;
        float tt[16];
#pragma unroll
        for (int r = 0; r < 16; r++) {
            float acc = bol[r];
#pragma unroll
            for (int c = 0; c < 16; c++) acc = fmaf(a[c], wo[r * 16 + c], acc);
            tt[r] = fmaxf(acc, 0.f);
        }
#pragma unroll
        for (int r = 0; r < 16; r++) a[r] += (r < i) ? tt[r] : 0.f;
        float mu = bfl[0], al = bfl[1];
#pragma unroll
        for (int c = 0; c < 16; c++) { mu = fmaf(a[c], wf[c], mu); al = fmaf(a[c], wf[16 + c], al); }
        out[((size_t)(b * Nn + n)) * Dd + i] = (xin - mu) * __expf(-al);
        atomicAdd(logdet + b * Nn + n, -al);
    }
}

extern "C" void kernel_launch(void* const* d_in, const int* in_sizes, int n_in,
                              void* d_out, int out_size, void* d_ws, size_t ws_size,
                              hipStream_t stream) {
    const float* X  = (const float*)d_in[0];
    const float* ip = (const float*)d_in[1];
    const float* Wq = (const float*)d_in[2];
    const float* bq = (const float*)d_in[3];
    const float* Wk = (const float*)d_in[4];
    const float* bk = (const float*)d_in[5];
    const float* Wv = (const float*)d_in[6];
    const float* bv = (const float*)d_in[7];
    const float* Wo = (const float*)d_in[8];
    const float* bo = (const float*)d_in[9];
    const float* Wf = (const float*)d_in[10];
    const float* bf = (const float*)d_in[11];
    float* out = (float*)d_out;

    const size_t need = (size_t)NL * Bb * Nn * sizeof(float);   // 983 KB for als
    hipError_t e = hipFuncSetAttribute((const void*)gf_fused,
                                       hipFuncAttributeMaxDynamicSharedMemorySize,
                                       LDS_TOTAL);
    if (e == hipSuccess && ws_size >= need) {
        float* als = (float*)d_ws;
        gf_fused<<<dim3(NL, Bb), 1024, LDS_TOTAL, stream>>>(
            X, Wq, bq, Wk, bk, Wv, bv, Wo, bo, Wf, bf, als, out);
        gf_final<<<Bb, 1024, 0, stream>>>(X, ip, als, out);
    } else {
        gf_init<<<(Bb * Nn + 255) / 256, 256, 0, stream>>>(X, ip, out);
        gf_layer_fb<<<dim3(NL, Bb), 512, 0, stream>>>(
            X, Wq, bq, Wk, bk, Wv, bv, Wo, bo, Wf, bf, out);
    }
}

// Round 5
// 155.492 us; speedup vs baseline: 2.2354x; 1.0054x over previous
//
#include <hip/hip_runtime.h>
#include <math.h>

#define Bb 16
#define Nn 1024
#define Dd 16
#define NL 15

typedef __attribute__((ext_vector_type(8))) short short8;
typedef __attribute__((ext_vector_type(4))) float f32x4;
typedef __attribute__((ext_vector_type(16))) float f32x16;
typedef __attribute__((ext_vector_type(4))) unsigned uint4v;

#if __has_builtin(__builtin_amdgcn_exp2f)
#define EXP2(x) __builtin_amdgcn_exp2f(x)
#else
#define EXP2(x) exp2f(x)
#endif

// LDS layout (dynamic, 69632 B):
//   K   : [1024 keys][16 shorts]           offset 0      32768 B
//   V^T : [16 d][VSTR=1044 shorts]         offset 32768  33408 B (stride 522
//         dwords % 32 = 10 -> d rows hit distinct banks, conflict-free)
//   O   : 16 waves x [64 q][16 f32]        offset 0      65536 B (overlays
//         K+V after the attention loop; barrier guards the reuse)
//   rs  : 16 waves x [64 f32]              offset 65536   4096 B
#define VSTR 1044
#define V_OFF 32768
#define RS_OFF 65536
#define LDS_TOTAL 69632

// round-half-up fp32->bf16 (positive/small finite values here)
__device__ __forceinline__ unsigned pack2bf(float a, float b) {
    unsigned ua = __float_as_uint(a) + 0x8000u;
    unsigned ub = __float_as_uint(b) + 0x8000u;
    return (ua >> 16) | (ub & 0xffff0000u);
}
__device__ __forceinline__ unsigned short bf1(float a) {
    return (unsigned short)((__float_as_uint(a) + 0x8000u) >> 16);
}

__device__ __forceinline__ void project(const float* __restrict__ xrow,
                                        const float* __restrict__ W,
                                        const float* __restrict__ bias,
                                        int i, float* __restrict__ q) {
#pragma unroll
    for (int r = 0; r < 16; r++) q[r] = 0.f;
    for (int c = 0; c < i; c++) {
        float xc = xrow[c];
#pragma unroll
        for (int r = 0; r < 16; r++) q[r] = fmaf(xc, W[r * 16 + c], q[r]);
    }
#pragma unroll
    for (int r = 0; r < 16; r++) q[r] = (r < i) ? (q[r] + bias[r]) : 0.f;
}

__device__ __forceinline__ void load_row16(const float* __restrict__ p, float* __restrict__ x) {
    const float4* xp = (const float4*)p;
    float4 a = xp[0], b = xp[1], c = xp[2], d = xp[3];
    x[0]=a.x; x[1]=a.y; x[2]=a.z; x[3]=a.w;
    x[4]=b.x; x[5]=b.y; x[6]=b.z; x[7]=b.w;
    x[8]=c.x; x[9]=c.y; x[10]=c.z; x[11]=c.w;
    x[12]=d.x; x[13]=d.y; x[14]=d.z; x[15]=d.w;
}

// ---------------------------------------------------------------------------
// Fused: proj -> barrier -> per-wave flash attn, all-32x32x16 MFMA.
// QK C-frag (exp'd, packed) is reused BIT-IDENTICALLY as the PV A-frag under
// a permuted key ordering; V B-frags are loaded to match (2 x b64 at +4h/+8).
// No P transpose, no P LDS, no masked loads, no intra-loop barriers.
// grid (NL, Bb), 1024 threads (16 waves, 64 queries/wave).
// ---------------------------------------------------------------------------
__launch_bounds__(1024, 4)
__global__ void gf_fused(const float* __restrict__ X,
                         const float* __restrict__ Wq, const float* __restrict__ bq,
                         const float* __restrict__ Wk, const float* __restrict__ bk,
                         const float* __restrict__ Wv, const float* __restrict__ bv,
                         const float* __restrict__ Wo, const float* __restrict__ bo,
                         const float* __restrict__ Wf, const float* __restrict__ bf,
                         float* __restrict__ als, float* __restrict__ out) {
    extern __shared__ char smem[];
    const int l = blockIdx.x, b = blockIdx.y, i = l + 1;
    const int t = threadIdx.x;
    const int wid = t >> 6, lane = t & 63;
    const int q31 = lane & 31, h = lane >> 5;
    const float qscale = 1.4426950408889634f * rsqrtf((float)i);

    unsigned short* Ksh = (unsigned short*)smem;
    unsigned short* Vsh = (unsigned short*)(smem + V_OFF);

    const float* Xb  = X  + (size_t)b * Nn * Dd;
    const float* wq  = Wq + l * 256;  const float* bql = bq + l * 16;
    const float* wk  = Wk + l * 256;  const float* bkl = bk + l * 16;
    const float* wvp = Wv + l * 256;  const float* bvl = bv + l * 16;
    const float* wo  = Wo + l * 256;  const float* bol = bo + l * 16;
    const float* wf  = Wf + l * 32;   const float* bfl = bf + l * 2;

    // ---------------- proj phase: thread t = row n = t ----------------
    unsigned qu[8];                       // Q row t, bf16-packed (kept in regs)
    {
        float xr[16]; load_row16(Xb + (size_t)t * Dd, xr);
        float tmp[16];
        unsigned u[8];

        project(xr, wk, bkl, i, tmp);
#pragma unroll
        for (int r = 0; r < 8; r++) u[r] = pack2bf(tmp[2*r], tmp[2*r+1]);
        {
            uint4* kd = (uint4*)(Ksh + t * 16);
            kd[0] = make_uint4(u[0], u[1], u[2], u[3]);
            kd[1] = make_uint4(u[4], u[5], u[6], u[7]);
        }

        project(xr, wvp, bvl, i, tmp);
#pragma unroll
        for (int d = 0; d < 16; d++) Vsh[d * VSTR + t] = bf1(tmp[d]);

        project(xr, wq, bql, i, tmp);
#pragma unroll
        for (int r = 0; r < 8; r++) qu[r] = pack2bf(tmp[2*r] * qscale, tmp[2*r+1] * qscale);
    }
    __syncthreads();

    // ---- Q B-frags via same-wave shuffles (wave wid owns rows wid*64..+63) --
    short8 qf0, qf1;
    {
        unsigned d0[4], d1[4];
#pragma unroll
        for (int j = 0; j < 4; j++) {
            unsigned lo = __shfl(qu[j], q31);
            unsigned hi = __shfl(qu[4 + j], q31);
            d0[j] = h ? hi : lo;
            lo = __shfl(qu[j], 32 + q31);
            hi = __shfl(qu[4 + j], 32 + q31);
            d1[j] = h ? hi : lo;
        }
        uint4v v0 = {d0[0], d0[1], d0[2], d0[3]};
        uint4v v1 = {d1[0], d1[1], d1[2], d1[3]};
        qf0 = __builtin_bit_cast(short8, v0);
        qf1 = __builtin_bit_cast(short8, v1);
    }

    // ---------------- attention loop ----------------
    f32x16 zf16 = {};
    f32x16 D0 = {}, D1 = {};
    float rs0 = 0.f, rs1 = 0.f;

    const unsigned short* Kp   = Ksh + (size_t)q31 * 16 + h * 8;  // A: K[key][8h+j]
    const unsigned short* Vrow = Vsh + (size_t)(q31 & 15) * VSTR; // B: V^T row d

    short8 kf = *(const short8*)Kp;

    for (int kb = 0; kb < Nn; kb += 32) {
        short8 kfn = *(const short8*)(Kp + (size_t)((kb + 32) & (Nn - 1)) * 16);

        f32x16 s0 = __builtin_amdgcn_mfma_f32_32x32x16_bf16(kf, qf0, zf16, 0, 0, 0);
        f32x16 s1 = __builtin_amdgcn_mfma_f32_32x32x16_bf16(kf, qf1, zf16, 0, 0, 0);
        kf = kfn;

        unsigned p0[8], p1[8];
#pragma unroll
        for (int g = 0; g < 4; g++) {
            float e0 = EXP2(s0[4*g+0]), e1 = EXP2(s0[4*g+1]);
            float e2 = EXP2(s0[4*g+2]), e3 = EXP2(s0[4*g+3]);
            rs0 += (e0 + e1) + (e2 + e3);
            p0[2*g]   = pack2bf(e0, e1);
            p0[2*g+1] = pack2bf(e2, e3);
        }
#pragma unroll
        for (int g = 0; g < 4; g++) {
            float e0 = EXP2(s1[4*g+0]), e1 = EXP2(s1[4*g+1]);
            float e2 = EXP2(s1[4*g+2]), e3 = EXP2(s1[4*g+3]);
            rs1 += (e0 + e1) + (e2 + e3);
            p1[2*g]   = pack2bf(e0, e1);
            p1[2*g+1] = pack2bf(e2, e3);
        }

        // PV: two 16-key sub-chunks; packed C-frag dwords ARE the A-frags.
#pragma unroll
        for (int s = 0; s < 2; s++) {
            const unsigned short* vb = Vrow + kb + 16*s + 4*h;
            uint2 va = *(const uint2*)vb;        // keys base+4h+0..3
            uint2 vc = *(const uint2*)(vb + 8);  // keys base+8+4h+0..3
            uint4v vv = {va.x, va.y, vc.x, vc.y};
            short8 vf = __builtin_bit_cast(short8, vv);
            uint4v a0 = {p0[4*s], p0[4*s+1], p0[4*s+2], p0[4*s+3]};
            uint4v a1 = {p1[4*s], p1[4*s+1], p1[4*s+2], p1[4*s+3]};
            D0 = __builtin_amdgcn_mfma_f32_32x32x16_bf16(__builtin_bit_cast(short8, a0), vf, D0, 0, 0, 0);
            D1 = __builtin_amdgcn_mfma_f32_32x32x16_bf16(__builtin_bit_cast(short8, a1), vf, D1, 0, 0, 0);
        }
    }

    rs0 += __shfl_xor(rs0, 32);
    rs1 += __shfl_xor(rs1, 32);

    __syncthreads();   // all waves done with K/V before region reuse

    // ---- stage O (C-layout -> row-major rows of 16 f32) + rs, wave-local ----
    float* Ow = (float*)smem + wid * 1024;          // 64 q x 16 f32
    if (q31 < 16) {
#pragma unroll
        for (int r = 0; r < 16; r++) {
            int m = (r & 3) + 8 * (r >> 2) + 4 * h;
            Ow[m * 16 + q31]        = D0[r];
            Ow[(m + 32) * 16 + q31] = D1[r];
        }
    }
    float* Rw = (float*)(smem + RS_OFF) + wid * 64;
    if (h == 0) { Rw[q31] = rs0; Rw[32 + q31] = rs1; }

    // ---------------- epilogue (thread t = query n = t) ----------------
    {
        float xr[16]; load_row16(Xb + (size_t)t * Dd, xr);
        float q[16];  project(xr, wq, bql, i, q);
        const float* orow = (const float*)smem + wid * 1024 + lane * 16;
        const float  inv  = 1.f / Rw[lane];

        float a[16];
#pragma unroll
        for (int c = 0; c < 16; c++) a[c] = q[c] + orow[c] * inv;

        float tt[16];
#pragma unroll
        for (int r = 0; r < 16; r++) {
            float acc = bol[r];
#pragma unroll
            for (int c = 0; c < 16; c++) acc = fmaf(a[c], wo[r * 16 + c], acc);
            tt[r] = fmaxf(acc, 0.f);
        }
#pragma unroll
        for (int r = 0; r < 16; r++) a[r] += (r < i) ? tt[r] : 0.f;

        float mu = bfl[0], al = bfl[1];
#pragma unroll
        for (int c = 0; c < 16; c++) {
            mu = fmaf(a[c], wf[c], mu);
            al = fmaf(a[c], wf[16 + c], al);
        }
        out[((size_t)(b * Nn + t)) * Dd + i] = (xr[i] - mu) * __expf(-al);
        als[(size_t)l * (Bb * Nn) + b * Nn + t] = al;
    }
}

// ---------------------------------------------------------------------------
// Final: layer-0 Z + logdet = -(alpha0 + sum_l al)   (no atomics)
// ---------------------------------------------------------------------------
__launch_bounds__(1024)
__global__ void gf_final(const float* __restrict__ X, const float* __restrict__ ip,
                         const float* __restrict__ als, float* __restrict__ out) {
    const int idx = blockIdx.x * 1024 + threadIdx.x;     // 0..Bb*Nn-1
    const float mu = ip[0], a0 = ip[1];
    float x0 = X[(size_t)idx * Dd];
    out[(size_t)idx * Dd] = (x0 - mu) * __expf(-a0);
    float ld = -a0;
#pragma unroll
    for (int l = 0; l < NL; l++) ld -= als[(size_t)l * (Bb * Nn) + idx];
    out[(size_t)Bb * Nn * Dd + idx] = ld;
}

// ---------------------------------------------------------------------------
// Fallback path (R1): init + fp32 kernel, if big dynamic LDS / ws unavailable
// ---------------------------------------------------------------------------
__global__ void gf_init(const float* __restrict__ X, const float* __restrict__ ip,
                        float* __restrict__ out) {
    int idx = blockIdx.x * blockDim.x + threadIdx.x;
    if (idx >= Bb * Nn) return;
    float mu = ip[0], alpha = ip[1];
    float x0 = X[(size_t)idx * Dd];
    out[(size_t)idx * Dd] = (x0 - mu) * __expf(-alpha);
    out[(size_t)Bb * Nn * Dd + idx] = -alpha;
}

__launch_bounds__(512, 2)
__global__ void gf_layer_fb(const float* __restrict__ X,
                            const float* __restrict__ Wq, const float* __restrict__ bq,
                            const float* __restrict__ Wk, const float* __restrict__ bk,
                            const float* __restrict__ Wv, const float* __restrict__ bv,
                            const float* __restrict__ Wo, const float* __restrict__ bo,
                            const float* __restrict__ Wf, const float* __restrict__ bf,
                            float* __restrict__ out) {
    const int l = blockIdx.x, b = blockIdx.y, i = l + 1, t = threadIdx.x;
    const float rscale = rsqrtf((float)i);
    __shared__ float Ksh[512 * 16];
    __shared__ float Vsh[512 * 16];
    const float* Xb = X + (size_t)b * Nn * Dd;
    const float* wq = Wq + l * 256; const float* wk = Wk + l * 256;
    const float* wv = Wv + l * 256; const float* wo = Wo + l * 256;
    const float* wf = Wf + l * 32;
    const float* bql = bq + l * 16; const float* bkl = bk + l * 16;
    const float* bvl = bv + l * 16; const float* bol = bo + l * 16;
    const float* bfl = bf + l * 2;
    const int n0 = t, n1 = t + 512;
    float q0[16], q1[16], xi0, xi1;
    {
        float xr[16];
        load_row16(Xb + (size_t)n0 * Dd, xr); xi0 = xr[i]; project(xr, wq, bql, i, q0);
        load_row16(Xb + (size_t)n1 * Dd, xr); xi1 = xr[i]; project(xr, wq, bql, i, q1);
    }
    float o0[16], o1[16];
#pragma unroll
    for (int c = 0; c < 16; c++) { o0[c] = 0.f; o1[c] = 0.f; }
    float ls0 = 0.f, ls1 = 0.f;
    for (int ch = 0; ch < 2; ch++) {
        float kr[16], vr[16];
        {
            float kx[16];
            load_row16(Xb + (size_t)(ch * 512 + t) * Dd, kx);
            project(kx, wk, bkl, i, kr);
            project(kx, wv, bvl, i, vr);
        }
        __syncthreads();
#pragma unroll
        for (int j = 0; j < 4; j++) {
            ((float4*)&Ksh[t * 16])[j] = ((float4*)kr)[j];
            ((float4*)&Vsh[t * 16])[j] = ((float4*)vr)[j];
        }
        __syncthreads();
        for (int k = 0; k < 512; k++) {
            float kk[16], vv[16];
#pragma unroll
            for (int j = 0; j < 4; j++) ((float4*)kk)[j] = ((const float4*)&Ksh[k * 16])[j];
            float s0 = 0.f, s1 = 0.f;
#pragma unroll
            for (int c = 0; c < 16; c++) { s0 = fmaf(q0[c], kk[c], s0); s1 = fmaf(q1[c], kk[c], s1); }
            float p0 = __expf(s0 * rscale), p1 = __expf(s1 * rscale);
            ls0 += p0; ls1 += p1;
#pragma unroll
            for (int j = 0; j < 4; j++) ((float4*)vv)[j] = ((const float4*)&Vsh[k * 16])[j];
#pragma unroll
            for (int c = 0; c < 16; c++) { o0[c] = fmaf(p0, vv[c], o0[c]); o1[c] = fmaf(p1, vv[c], o1[c]); }
        }
        __syncthreads();
    }
    float* logdet = out + (size_t)Bb * Nn * Dd;
#pragma unroll
    for (int rowsel = 0; rowsel < 2; rowsel++) {
        const float* qr = rowsel ? q1 : q0; const float* orr = rowsel ? o1 : o0;
        float lsum = rowsel ? ls1 : ls0; float xin = rowsel ? xi1 : xi0;
        int n = rowsel ? n1 : n0;
        float a[16]; float inv = 1.f / lsum;
#pragma unroll
        for (int c = 0; c < 16; c++) a[c] = qr[c] + orr[c] * inv;
        float tt[16];
#pragma unroll
        for (int r = 0; r < 16; r++) {
            float acc = bol[r];
#pragma unroll
            for (int c = 0; c < 16; c++) acc = fmaf(a[c], wo[r * 16 + c], acc);
            tt[r] = fmaxf(acc, 0.f);
        }
#pragma unroll
        for (int r = 0; r < 16; r++) a[r] += (r < i) ? tt[r] : 0.f;
        float mu = bfl[0], al = bfl[1];
#pragma unroll
        for (int c = 0; c < 16; c++) { mu = fmaf(a[c], wf[c], mu); al = fmaf(a[c], wf[16 + c], al); }
        out[((size_t)(b * Nn + n)) * Dd + i] = (xin - mu) * __expf(-al);
        atomicAdd(logdet + b * Nn + n, -al);
    }
}

extern "C" void kernel_launch(void* const* d_in, const int* in_sizes, int n_in,
                              void* d_out, int out_size, void* d_ws, size_t ws_size,
                              hipStream_t stream) {
    const float* X  = (const float*)d_in[0];
    const float* ip = (const float*)d_in[1];
    const float* Wq = (const float*)d_in[2];
    const float* bq = (const float*)d_in[3];
    const float* Wk = (const float*)d_in[4];
    const float* bk = (const float*)d_in[5];
    const float* Wv = (const float*)d_in[6];
    const float* bv = (const float*)d_in[7];
    const float* Wo = (const float*)d_in[8];
    const float* bo = (const float*)d_in[9];
    const float* Wf = (const float*)d_in[10];
    const float* bf = (const float*)d_in[11];
    float* out = (float*)d_out;

    const size_t need = (size_t)NL * Bb * Nn * sizeof(float);   // 983 KB for als
    hipError_t e = hipFuncSetAttribute((const void*)gf_fused,
                                       hipFuncAttributeMaxDynamicSharedMemorySize,
                                       LDS_TOTAL);
    if (e == hipSuccess && ws_size >= need) {
        float* als = (float*)d_ws;
        gf_fused<<<dim3(NL, Bb), 1024, LDS_TOTAL, stream>>>(
            X, Wq, bq, Wk, bk, Wv, bv, Wo, bo, Wf, bf, als, out);
        gf_final<<<Bb, 1024, 0, stream>>>(X, ip, als, out);
    } else {
        gf_init<<<(Bb * Nn + 255) / 256, 256, 0, stream>>>(X, ip, out);
        gf_layer_fb<<<dim3(NL, Bb), 512, 0, stream>>>(
            X, Wq, bq, Wk, bk, Wv, bv, Wo, bo, Wf, bf, out);
    }
}